// Round 1
// baseline (249.157 us; speedup 1.0000x reference)
//
#include <hip/hip_runtime.h>
#include <hip/hip_bf16.h>

#define BB 32
#define INP 1024
#define WIDTH 256
#define OUTP 1024
#define NE 8
#define HW 196
#define HH 14
#define EPS 1e-5f

#define S1 (WIDTH * INP)        // 262144
#define S2 (WIDTH * WIDTH * 9)  // 589824
#define S3 (OUTP * WIDTH)       // 262144

typedef __attribute__((ext_vector_type(8))) short bf16x8;
typedef __attribute__((ext_vector_type(4))) float f32x4;
typedef __attribute__((ext_vector_type(8))) unsigned short u16x8;

// Swizzled operand layout: tile = 16 rows x 32 k = 512 bf16 = 1 KB.
// Element (r,k) at lane*8 + (k&7), lane = (r&15) | (((k>>3)&3)<<4).

// Counted-vmcnt drain: keep newest batch in flight across the barrier (T4).
#define VMCNT(n) asm volatile("s_waitcnt vmcnt(" #n ")" ::: "memory")

__device__ __forceinline__ unsigned short f2bf_bits(float f) {
    unsigned u = __float_as_uint(f);
    u += 0x7FFFu + ((u >> 16) & 1u);   // RNE
    return (unsigned short)(u >> 16);
}
__device__ __forceinline__ float bf2f(unsigned short h) {
    return __uint_as_float((unsigned)h << 16);
}

#if defined(__has_builtin)
#if __has_builtin(__builtin_amdgcn_global_load_lds)
#define HAVE_GLL 1
#endif
#endif
__device__ __forceinline__ void gl2lds(const unsigned short* g, unsigned short* l,
                                       int lane) {
#ifdef HAVE_GLL
    __builtin_amdgcn_global_load_lds(
        (const __attribute__((address_space(1))) unsigned int*)(const void*)g,
        (__attribute__((address_space(3))) unsigned int*)(void*)l, 16, 0, 0);
#else
    *(u16x8*)(l + lane * 8) = *(const u16x8*)g;
#endif
}

// ---------------------------------------------------------------------------
// In-block routing (8-sample group g): srw[s*8+e] = sigmoid(scale*(v@W)+b).
// First 4 waves only participate meaningfully; block is 256 threads.
// ---------------------------------------------------------------------------
__device__ __forceinline__ void block_route(
    const float* __restrict__ vec, const float* __restrict__ W,
    const float* __restrict__ bias, float scale, int C, int g,
    float* srw, int tid) {
    int wv = tid >> 6, lane = tid & 63;
    float p0[NE], p1[NE];
#pragma unroll
    for (int e = 0; e < NE; e++) { p0[e] = 0.f; p1[e] = 0.f; }
    const float* v0 = vec + (size_t)(g * 8 + wv * 2) * C;
    const float* v1 = v0 + C;
    for (int c = lane; c < C; c += 64) {
        float4 wa = *(const float4*)(W + c * 8);
        float4 wb = *(const float4*)(W + c * 8 + 4);
        float m0 = v0[c], m1 = v1[c];
        p0[0] += m0 * wa.x; p0[1] += m0 * wa.y; p0[2] += m0 * wa.z; p0[3] += m0 * wa.w;
        p0[4] += m0 * wb.x; p0[5] += m0 * wb.y; p0[6] += m0 * wb.z; p0[7] += m0 * wb.w;
        p1[0] += m1 * wa.x; p1[1] += m1 * wa.y; p1[2] += m1 * wa.z; p1[3] += m1 * wa.w;
        p1[4] += m1 * wb.x; p1[5] += m1 * wb.y; p1[6] += m1 * wb.z; p1[7] += m1 * wb.w;
    }
#pragma unroll
    for (int j = 1; j < 64; j <<= 1) {
#pragma unroll
        for (int e = 0; e < NE; e++) {
            p0[e] += __shfl_xor(p0[e], j, 64);
            p1[e] += __shfl_xor(p1[e], j, 64);
        }
    }
    if (lane == 0) {
#pragma unroll
        for (int e = 0; e < NE; e++) {
            srw[(wv * 2) * 8 + e] = 1.0f / (1.0f + expf(-(scale * p0[e] + bias[e])));
            srw[(wv * 2 + 1) * 8 + e] = 1.0f / (1.0f + expf(-(scale * p1[e] + bias[e])));
        }
    }
    __syncthreads();
}

// ---------------------------------------------------------------------------
// Merged pre-kernel. Blocks [0,256): transpose+mean of x -> swizzled xb +
// mean1. Blocks [256,2304): permute w2 -> k-ordered bf16 wb2.
// ---------------------------------------------------------------------------
__global__ __launch_bounds__(256) void pre_kernel(
    const float* __restrict__ x, unsigned short* __restrict__ xb,
    float* __restrict__ mean1,
    const float* __restrict__ w2, unsigned short* __restrict__ wb2) {
    __shared__ __align__(16) char smem[128 * 17 * 4];
    int blk = blockIdx.x, t = threadIdx.x;
    if (blk < 256) {
        float (*lt)[17] = (float(*)[17])smem;
        int b = blk >> 3, yq = blk & 7, c0 = yq * 128;
        int cr = t >> 1, half = t & 1;
        const float* src = x + ((size_t)(b * INP + c0 + cr)) * HW;
        float msum = 0.f;
        int j = t >> 4, nl = t & 15;
        for (int pg = 0; pg < 14; pg++) {
            int p0 = pg * 16 + half * 8;
            float vv[8];
            if (pg < 12) {
                float4 a = *(const float4*)(src + p0);
                float4 c = *(const float4*)(src + p0 + 4);
                vv[0] = a.x; vv[1] = a.y; vv[2] = a.z; vv[3] = a.w;
                vv[4] = c.x; vv[5] = c.y; vv[6] = c.z; vv[7] = c.w;
            } else {
#pragma unroll
                for (int i = 0; i < 8; i++) {
                    int p = p0 + i;
                    vv[i] = (p < HW) ? src[p] : 0.f;
                }
            }
#pragma unroll
            for (int i = 0; i < 8; i++) { msum += vv[i]; lt[cr][half * 8 + i] = vv[i]; }
            __syncthreads();
            unsigned short pk[8];
#pragma unroll
            for (int i = 0; i < 8; i++) pk[i] = f2bf_bits(lt[j * 8 + i][nl]);
            size_t tile = ((size_t)b * 14 + pg) * 32 + (size_t)(yq * 4 + (j >> 2));
            int lane = nl | ((j & 3) << 4);
            *(u16x8*)(xb + tile * 512 + lane * 8) = *(u16x8*)pk;
            __syncthreads();
        }
        float other = __shfl_xor(msum, 1, 64);
        if (half == 0) mean1[b * INP + c0 + cr] = (msum + other) * (1.0f / (float)HW);
    } else {
        unsigned short* lds = (unsigned short*)smem;
        int eo = blk - 256;
        const float* src = w2 + (size_t)eo * 2304 + (size_t)t * 9;
#pragma unroll
        for (int t9 = 0; t9 < 9; t9++) lds[t9 * 256 + t] = f2bf_bits(src[t9]);
        __syncthreads();
        unsigned short* dst = wb2 + (size_t)eo * 2304;
        for (int j = t; j < 288; j += 256)
            *(u16x8*)(dst + j * 8) = *(const u16x8*)(lds + j * 8);
    }
}

// ---------------------------------------------------------------------------
// Combine (contiguous-k fp32 experts, w1/w3) + fused routing.
// grid = (Mt*Kt/4, 4 sample groups), 256 threads.
// ---------------------------------------------------------------------------
__global__ __launch_bounds__(256) void combine_cont_r(
    const float* __restrict__ w, const float* __restrict__ vec,
    const float* __restrict__ rW, const float* __restrict__ rB, float scale, int C,
    unsigned short* __restrict__ cw, int S, int Mt, int Kt) {
    __shared__ float srw[64];
    int tid = threadIdx.x, wv = tid >> 6, lane = tid & 63, ml = lane & 15, k8l = lane >> 4;
    int g = blockIdx.y;
    block_route(vec, rW, rB, scale, C, g, srw, tid);
    int kq = Kt >> 2;
    int mt = blockIdx.x / kq, kt = (blockIdx.x - mt * kq) * 4 + wv;
    int K = Kt * 32;
    const float* src = w + (size_t)(mt * 16 + ml) * K + kt * 32 + k8l * 8;
    float v[NE][8];
#pragma unroll
    for (int e = 0; e < NE; e++) {
        float4 a = *(const float4*)(src + (size_t)e * S);
        float4 c = *(const float4*)(src + (size_t)e * S + 4);
        v[e][0] = a.x; v[e][1] = a.y; v[e][2] = a.z; v[e][3] = a.w;
        v[e][4] = c.x; v[e][5] = c.y; v[e][6] = c.z; v[e][7] = c.w;
    }
    size_t dto = ((size_t)mt * Kt + kt) * 512 + (size_t)lane * 8;
    size_t bstr = (size_t)Mt * Kt * 512;
    for (int bl = 0; bl < 8; bl++) {
        int b = g * 8 + bl;
        float acc[8];
#pragma unroll
        for (int jj = 0; jj < 8; jj++) acc[jj] = 0.f;
#pragma unroll
        for (int e = 0; e < NE; e++) {
            float r = srw[bl * NE + e];
#pragma unroll
            for (int jj = 0; jj < 8; jj++) acc[jj] += r * v[e][jj];
        }
        u16x8 o;
#pragma unroll
        for (int jj = 0; jj < 8; jj++) o[jj] = f2bf_bits(acc[jj]);
        *(u16x8*)(cw + (size_t)b * bstr + dto) = o;
    }
}

// ---------------------------------------------------------------------------
// Combine w2 (k-ordered bf16 wb2) + fused routing. grid = (288, 4 groups).
// ---------------------------------------------------------------------------
__global__ __launch_bounds__(256) void combine_w2_r(
    const unsigned short* __restrict__ wb2, const float* __restrict__ vec,
    const float* __restrict__ rW, const float* __restrict__ rB, float scale,
    unsigned short* __restrict__ cw) {
    __shared__ float srw[64];
    int tid = threadIdx.x, wv = tid >> 6, lane = tid & 63, ol = lane & 15, g4 = lane >> 4;
    int g = blockIdx.y;
    block_route(vec, rW, rB, scale, 256, g, srw, tid);
    int ot = blockIdx.x / 18, kt = (blockIdx.x - ot * 18) * 4 + wv;
    const unsigned short* src = wb2 + (size_t)(ot * 16 + ol) * 2304 + kt * 32 + g4 * 8;
    float v[NE][8];
#pragma unroll
    for (int e = 0; e < NE; e++) {
        u16x8 raw = *(const u16x8*)(src + (size_t)e * S2);
#pragma unroll
        for (int jj = 0; jj < 8; jj++) v[e][jj] = bf2f(raw[jj]);
    }
    size_t dto = ((size_t)ot * 72 + kt) * 512 + (size_t)lane * 8;
    for (int bl = 0; bl < 8; bl++) {
        int b = g * 8 + bl;
        float acc[8];
#pragma unroll
        for (int jj = 0; jj < 8; jj++) acc[jj] = 0.f;
#pragma unroll
        for (int e = 0; e < NE; e++) {
            float r = srw[bl * NE + e];
#pragma unroll
            for (int jj = 0; jj < 8; jj++) acc[jj] += r * v[e][jj];
        }
        u16x8 out;
#pragma unroll
        for (int jj = 0; jj < 8; jj++) out[jj] = f2bf_bits(acc[jj]);
        *(u16x8*)(cw + (size_t)b * (16 * 72 * 512) + dto) = out;
    }
}

// ---------------------------------------------------------------------------
// Fused epilogue: BN + ReLU -> swizzled bf16 act + per-channel sum atomics.
// ---------------------------------------------------------------------------
__device__ __forceinline__ void epilogue_act(
    const f32x4* acc, int b, int mt, int nh, int lo, int g4,
    const float* __restrict__ g, const float* __restrict__ be,
    const float* __restrict__ mu, const float* __restrict__ var,
    unsigned short* __restrict__ actout, float* __restrict__ msum) {
    int c0 = mt * 16 + g4 * 4;
    float sc[4], sh[4];
#pragma unroll
    for (int r = 0; r < 4; r++) {
        float iv = rsqrtf(var[c0 + r] + EPS) * g[c0 + r];
        sc[r] = iv;
        sh[r] = be[c0 + r] - mu[c0 + r] * iv;
    }
    float ms[4] = {0.f, 0.f, 0.f, 0.f};
    int ktc = mt >> 1;
    int lanehi = ((mt * 2 + (g4 >> 1)) & 3) << 4;
#pragma unroll
    for (int t = 0; t < 7; t++) {
        int nt = nh * 7 + t;
        int n = nt * 16 + lo;
        float v[4];
#pragma unroll
        for (int r = 0; r < 4; r++) {
            float val = acc[t][r] * sc[r] + sh[r];
            val = fmaxf(val, 0.f);
            if (n >= HW) val = 0.f;
            v[r] = val;
            ms[r] += val;
        }
        unsigned p01 = (unsigned)f2bf_bits(v[0]) | ((unsigned)f2bf_bits(v[1]) << 16);
        unsigned p23 = (unsigned)f2bf_bits(v[2]) | ((unsigned)f2bf_bits(v[3]) << 16);
        size_t off = (((size_t)(b * 14 + nt)) * 8 + ktc) * 512 + (size_t)(lo | lanehi) * 8 + (g4 & 1) * 4;
        *(uint2*)(actout + off) = make_uint2(p01, p23);
    }
#pragma unroll
    for (int r = 0; r < 4; r++) {
        float s = ms[r];
        s += __shfl_xor(s, 1, 64);
        s += __shfl_xor(s, 2, 64);
        s += __shfl_xor(s, 4, 64);
        s += __shfl_xor(s, 8, 64);
        if (lo == 0) atomicAdd(&msum[b * 256 + c0 + r], s);
    }
}

// ---------------------------------------------------------------------------
// Stage-1 fused GEMM, 512 threads = 8 waves, in-block split-K2:
// group = wave>>2 computes k-steps of parity `group`. 8 LDS buffers,
// distance-2 staging, counted vmcnt + raw s_barrier (T3+T4): newest
// global_load_lds batch stays in flight across the barrier. grid (BB,4,2).
// ---------------------------------------------------------------------------
__global__ __launch_bounds__(512) void gemm1_fused(
    const unsigned short* __restrict__ Bsw, const unsigned short* __restrict__ Asw,
    const float* __restrict__ g, const float* __restrict__ be,
    const float* __restrict__ mu, const float* __restrict__ var,
    unsigned short* __restrict__ actout, float* __restrict__ msum) {
    __shared__ __align__(16) unsigned short lAb[8][4 * 512];   // 32 KB
    __shared__ __align__(16) unsigned short lBb[8][7 * 512];   // 56 KB
    const int Kt = 32;
    int b = blockIdx.x, mh = blockIdx.y, nh = blockIdx.z;
    int tid = threadIdx.x, wv = tid >> 6, grp = wv >> 2, wl = wv & 3;
    int lane = tid & 63, lo = lane & 15, g4 = lane >> 4;
    const unsigned short* Ab = Asw + (size_t)(b * 16 + mh * 4) * Kt * 512;
    const unsigned short* Bb = Bsw + (size_t)(b * 14 + nh * 7) * Kt * 512;
    f32x4 acc[7];
#pragma unroll
    for (int t = 0; t < 7; t++) acc[t] = {0.f, 0.f, 0.f, 0.f};

    auto stage = [&](int kt) {
        unsigned short* lA = lAb[kt & 7];
        unsigned short* lB = lBb[kt & 7];
        gl2lds(Ab + ((size_t)wl * Kt + kt) * 512 + lane * 8, lA + wl * 512, lane);
        gl2lds(Bb + ((size_t)wl * Kt + kt) * 512 + lane * 8, lB + wl * 512, lane);
        if (wl < 3)
            gl2lds(Bb + ((size_t)(4 + wl) * Kt + kt) * 512 + lane * 8, lB + (4 + wl) * 512, lane);
    };
    auto compute = [&](int kt) {
        const unsigned short* lA = lAb[kt & 7];
        const unsigned short* lB = lBb[kt & 7];
        bf16x8 a0 = *(const bf16x8*)(lA + wl * 512 + lane * 8);
#pragma unroll
        for (int t = 0; t < 7; t++) {
            bf16x8 bt = *(const bf16x8*)(lB + t * 512 + lane * 8);
            acc[t] = __builtin_amdgcn_mfma_f32_16x16x32_bf16(a0, bt, acc[t], 0, 0, 0);
        }
    };

    // Prologue: two batches of this group's parity in flight.
    stage(grp);
    stage(grp + 2);
    for (int kp = 0; kp < 16; kp++) {
        int c = 2 * kp + grp;
        // Drain everything older than the newest outstanding batch; the batch
        // for step c must complete, the one for c+2 may stay in flight.
        if (c + 2 < 32) {
            if (wl < 3) VMCNT(3); else VMCNT(2);
        } else {
            VMCNT(0);
        }
        __builtin_amdgcn_s_barrier();
        int s = c + 4;
        if (s < 32) stage(s);
        compute(c);
    }
    // Cross-group reduction through (dead) B-staging LDS.
    __syncthreads();
    float* red = (float*)&lBb[0][0];   // 4*7*64*4 floats = 28672 B
    if (grp == 1) {
#pragma unroll
        for (int t = 0; t < 7; t++)
            *(f32x4*)(red + (((size_t)wl * 7 + t) * 64 + lane) * 4) = acc[t];
    }
    __syncthreads();
    if (grp == 0) {
#pragma unroll
        for (int t = 0; t < 7; t++) {
            f32x4 o = *(const f32x4*)(red + (((size_t)wl * 7 + t) * 64 + lane) * 4);
#pragma unroll
            for (int r = 0; r < 4; r++) acc[t][r] += o[r];
        }
        epilogue_act(acc, b, mh * 4 + wl, nh, lo, g4, g, be, mu, var, actout, msum);
    }
}

// ---------------------------------------------------------------------------
// Stage-2 fused GEMM (im2col gather staging), 512 threads, in-block split-K2,
// 8-buffer distance-2 pipeline with counted vmcnt. grid (BB, 4, 2).
// 72 k-steps (9 taps x 8 i-tiles).
// ---------------------------------------------------------------------------
__global__ __launch_bounds__(512) void gemm2_fused(
    const unsigned short* __restrict__ act, const unsigned short* __restrict__ cw2,
    const unsigned short* __restrict__ zpad,
    const float* __restrict__ g, const float* __restrict__ be,
    const float* __restrict__ mu, const float* __restrict__ var,
    unsigned short* __restrict__ actout, float* __restrict__ msum) {
    __shared__ __align__(16) unsigned short lAb[8][4 * 512];   // 32 KB
    __shared__ __align__(16) unsigned short lBb[8][7 * 512];   // 56 KB
    int b = blockIdx.x, mh = blockIdx.y, nh = blockIdx.z;
    int tid = threadIdx.x, wv = tid >> 6, grp = wv >> 2, wl = wv & 3;
    int lane = tid & 63, lo = lane & 15, g4 = lane >> 4;
    const unsigned short* Ab = cw2 + (size_t)(b * 16 + mh * 4) * 72 * 512;
    const unsigned short* actb = act + (size_t)b * 14 * 8 * 512;

    int p0 = (nh * 7 + wl) * 16 + lo;
    int py0 = p0 / HH, px0 = p0 - (p0 / HH) * HH;
    bool pv0 = p0 < HW;
    int p1 = (nh * 7 + wl + 4) * 16 + lo;
    int py1 = p1 / HH, px1 = p1 - (p1 / HH) * HH;
    bool pv1 = (wl < 3) && (p1 < HW);

    f32x4 acc[7];
#pragma unroll
    for (int t = 0; t < 7; t++) acc[t] = {0.f, 0.f, 0.f, 0.f};

    auto stage = [&](int kt) {
        unsigned short* lA = lAb[kt & 7];
        unsigned short* lB = lBb[kt & 7];
        gl2lds(Ab + ((size_t)wl * 72 + kt) * 512 + lane * 8, lA + wl * 512, lane);
        int t9 = kt >> 3;
        int dy = t9 / 3 - 1, dx = t9 - (t9 / 3) * 3 - 1;
        int itile = kt & 7;
        {
            int sy = py0 + dy, sx = px0 + dx;
            bool ok = pv0 && sy >= 0 && sy < HH && sx >= 0 && sx < HH;
            int ns = sy * HH + sx;
            const unsigned short* gp = ok
                ? actb + ((size_t)(ns >> 4) * 8 + itile) * 512 + (size_t)((ns & 15) | (g4 << 4)) * 8
                : zpad;
            gl2lds(gp, lB + wl * 512, lane);
        }
        if (wl < 3) {
            int sy = py1 + dy, sx = px1 + dx;
            bool ok = pv1 && sy >= 0 && sy < HH && sx >= 0 && sx < HH;
            int ns = sy * HH + sx;
            const unsigned short* gp = ok
                ? actb + ((size_t)(ns >> 4) * 8 + itile) * 512 + (size_t)((ns & 15) | (g4 << 4)) * 8
                : zpad;
            gl2lds(gp, lB + (wl + 4) * 512, lane);
        }
    };
    auto compute = [&](int kt) {
        const unsigned short* lA = lAb[kt & 7];
        const unsigned short* lB = lBb[kt & 7];
        bf16x8 a0 = *(const bf16x8*)(lA + wl * 512 + lane * 8);
#pragma unroll
        for (int t = 0; t < 7; t++) {
            bf16x8 bt = *(const bf16x8*)(lB + t * 512 + lane * 8);
            acc[t] = __builtin_amdgcn_mfma_f32_16x16x32_bf16(a0, bt, acc[t], 0, 0, 0);
        }
    };

    stage(grp);
    stage(grp + 2);
    for (int kp = 0; kp < 36; kp++) {
        int c = 2 * kp + grp;
        if (c + 2 < 72) {
            if (wl < 3) VMCNT(3); else VMCNT(2);
        } else {
            VMCNT(0);
        }
        __builtin_amdgcn_s_barrier();
        int s = c + 4;
        if (s < 72) stage(s);
        compute(c);
    }
    __syncthreads();
    float* red = (float*)&lBb[0][0];
    if (grp == 1) {
#pragma unroll
        for (int t = 0; t < 7; t++)
            *(f32x4*)(red + (((size_t)wl * 7 + t) * 64 + lane) * 4) = acc[t];
    }
    __syncthreads();
    if (grp == 0) {
#pragma unroll
        for (int t = 0; t < 7; t++) {
            f32x4 o = *(const f32x4*)(red + (((size_t)wl * 7 + t) * 64 + lane) * 4);
#pragma unroll
            for (int r = 0; r < 4; r++) acc[t][r] += o[r];
        }
        epilogue_act(acc, b, mh * 4 + wl, nh, lo, g4, g, be, mu, var, actout, msum);
    }
}

// ---------------------------------------------------------------------------
// Stage-3 GEMM, 512 threads, in-block split-K2, 8-buffer distance-2 pipeline,
// fused BN + bf16 residual (from swizzled xb) + ReLU -> fp32 NCHW.
// grid (BB, 16). K=256 (8 steps).
// ---------------------------------------------------------------------------
__global__ __launch_bounds__(512) void gemm3_fused(
    const unsigned short* __restrict__ Bsw, const unsigned short* __restrict__ Asw,
    const float* __restrict__ g, const float* __restrict__ be,
    const float* __restrict__ mu, const float* __restrict__ var,
    const unsigned short* __restrict__ xb, float* __restrict__ out) {
    __shared__ __align__(16) unsigned short lAb[8][8 * 512];   // 64 KB
    __shared__ __align__(16) unsigned short lBb[8][7 * 512];   // 56 KB
    int b = blockIdx.x, y = blockIdx.y, mh = y >> 1, nh = y & 1;
    int tid = threadIdx.x, wv = tid >> 6, grp = wv >> 2, wl = wv & 3;
    int lane = tid & 63, lo = lane & 15, g4 = lane >> 4;
    const unsigned short* Ab = Asw + (size_t)(b * 64 + mh * 8) * 8 * 512;
    const unsigned short* Bb = Bsw + (size_t)(b * 14 + nh * 7) * 8 * 512;
    f32x4 acc0[7], acc1[7];
#pragma unroll
    for (int t = 0; t < 7; t++) { acc0[t] = {0.f, 0.f, 0.f, 0.f}; acc1[t] = {0.f, 0.f, 0.f, 0.f}; }

    auto stage = [&](int kt) {
        unsigned short* lA = lAb[kt & 7];
        unsigned short* lB = lBb[kt & 7];
        gl2lds(Ab + ((size_t)wl * 8 + kt) * 512 + lane * 8, lA + wl * 512, lane);
        gl2lds(Ab + ((size_t)(wl + 4) * 8 + kt) * 512 + lane * 8, lA + (wl + 4) * 512, lane);
        gl2lds(Bb + ((size_t)wl * 8 + kt) * 512 + lane * 8, lB + wl * 512, lane);
        if (wl < 3)
            gl2lds(Bb + ((size_t)(4 + wl) * 8 + kt) * 512 + lane * 8, lB + (4 + wl) * 512, lane);
    };
    auto compute = [&](int kt) {
        const unsigned short* lA = lAb[kt & 7];
        const unsigned short* lB = lBb[kt & 7];
        bf16x8 a0 = *(const bf16x8*)(lA + wl * 512 + lane * 8);
        bf16x8 a1 = *(const bf16x8*)(lA + (wl + 4) * 512 + lane * 8);
#pragma unroll
        for (int t = 0; t < 7; t++) {
            bf16x8 bt = *(const bf16x8*)(lB + t * 512 + lane * 8);
            acc0[t] = __builtin_amdgcn_mfma_f32_16x16x32_bf16(a0, bt, acc0[t], 0, 0, 0);
            acc1[t] = __builtin_amdgcn_mfma_f32_16x16x32_bf16(a1, bt, acc1[t], 0, 0, 0);
        }
    };

    stage(grp);
    stage(grp + 2);
    for (int kp = 0; kp < 4; kp++) {
        int c = 2 * kp + grp;
        if (c + 2 < 8) {
            if (wl < 3) VMCNT(4); else VMCNT(3);
        } else {
            VMCNT(0);
        }
        __builtin_amdgcn_s_barrier();
        int s = c + 4;
        if (s < 8) stage(s);
        compute(c);
    }
    // Two-phase cross-group reduction via lBb (28672 B per phase).
    __syncthreads();
    float* red = (float*)&lBb[0][0];
    if (grp == 1) {
#pragma unroll
        for (int t = 0; t < 7; t++)
            *(f32x4*)(red + (((size_t)wl * 7 + t) * 64 + lane) * 4) = acc0[t];
    }
    __syncthreads();
    if (grp == 0) {
#pragma unroll
        for (int t = 0; t < 7; t++) {
            f32x4 o = *(const f32x4*)(red + (((size_t)wl * 7 + t) * 64 + lane) * 4);
#pragma unroll
            for (int r = 0; r < 4; r++) acc0[t][r] += o[r];
        }
    }
    __syncthreads();
    if (grp == 1) {
#pragma unroll
        for (int t = 0; t < 7; t++)
            *(f32x4*)(red + (((size_t)wl * 7 + t) * 64 + lane) * 4) = acc1[t];
    }
    __syncthreads();
    if (grp != 0) return;
#pragma unroll
    for (int t = 0; t < 7; t++) {
        f32x4 o = *(const f32x4*)(red + (((size_t)wl * 7 + t) * 64 + lane) * 4);
#pragma unroll
        for (int r = 0; r < 4; r++) acc1[t][r] += o[r];
    }

#pragma unroll
    for (int a = 0; a < 2; a++) {
        int mt = mh * 8 + wl + 4 * a;
        int c0 = mt * 16 + g4 * 4;
        float sc[4], sh[4];
#pragma unroll
        for (int r = 0; r < 4; r++) {
            float iv = rsqrtf(var[c0 + r] + EPS) * g[c0 + r];
            sc[r] = iv;
            sh[r] = be[c0 + r] - mu[c0 + r] * iv;
        }
        int ktc = mt >> 1;
        int lanehi = ((mt * 2 + (g4 >> 1)) & 3) << 4;
#pragma unroll
        for (int t = 0; t < 7; t++) {
            int nt = nh * 7 + t;
            int n = nt * 16 + lo;
            if (n >= HW) continue;
            // bf16 residual from swizzled xb (K-tiles of 32 over c=0..1023).
            const unsigned short* xr = xb + (((size_t)(b * 14 + nt)) * 32 + ktc) * 512
                                       + (size_t)(lo | lanehi) * 8 + (g4 & 1) * 4;
            uint2 rv = *(const uint2*)xr;
            float res[4] = {bf2f((unsigned short)(rv.x & 0xffff)),
                            bf2f((unsigned short)(rv.x >> 16)),
                            bf2f((unsigned short)(rv.y & 0xffff)),
                            bf2f((unsigned short)(rv.y >> 16))};
            f32x4 av = a ? acc1[t] : acc0[t];
#pragma unroll
            for (int r = 0; r < 4; r++) {
                size_t oidx = ((size_t)(b * OUTP + c0 + r)) * HW + n;
                float val = av[r] * sc[r] + sh[r] + res[r];
                out[oidx] = fmaxf(val, 0.f);
            }
        }
    }
}

// ---------------------------------------------------------------------------
extern "C" void kernel_launch(void* const* d_in, const int* in_sizes, int n_in,
                              void* d_out, int out_size, void* d_ws, size_t ws_size,
                              hipStream_t stream) {
    const float* x    = (const float*)d_in[0];
    const float* w1   = (const float*)d_in[1];
    const float* w2   = (const float*)d_in[2];
    const float* w3   = (const float*)d_in[3];
    const float* r1_w = (const float*)d_in[4];
    const float* r1_b = (const float*)d_in[5];
    const float* r2_w = (const float*)d_in[6];
    const float* r2_b = (const float*)d_in[7];
    const float* r3_w = (const float*)d_in[8];
    const float* r3_b = (const float*)d_in[9];
    const float* bn1_g = (const float*)d_in[10];
    const float* bn1_b = (const float*)d_in[11];
    const float* bn1_m = (const float*)d_in[12];
    const float* bn1_v = (const float*)d_in[13];
    const float* bn2_g = (const float*)d_in[14];
    const float* bn2_b = (const float*)d_in[15];
    const float* bn2_m = (const float*)d_in[16];
    const float* bn2_v = (const float*)d_in[17];
    const float* bn3_g = (const float*)d_in[18];
    const float* bn3_b = (const float*)d_in[19];
    const float* bn3_m = (const float*)d_in[20];
    const float* bn3_v = (const float*)d_in[21];
    float* out = (float*)d_out;

    // Workspace (~86.4 MB). cwX slot time-shared: cw1 (stage 1) then cw3
    // (stage 3; cw1 dead after gemm1). xb persists to gemm3 (bf16 residual).
    char* ws = (char*)d_ws;
    size_t off = 0;
    float* mean1 = (float*)(ws + off); off += (size_t)BB * INP * 4;
    float* msum2 = (float*)(ws + off); off += (size_t)BB * 256 * 4;
    float* msum3 = (float*)(ws + off); off += (size_t)BB * 256 * 4;
    unsigned short* zpad = (unsigned short*)(ws + off); off += 256;
    off = (off + 255) & ~(size_t)255;
    unsigned short* act1 = (unsigned short*)(ws + off); off += (size_t)BB * 14 * 8 * 512 * 2;  // 3.67 MB
    unsigned short* act2 = (unsigned short*)(ws + off); off += (size_t)BB * 14 * 8 * 512 * 2;  // 3.67 MB
    unsigned short* cw2 = (unsigned short*)(ws + off); off += (size_t)BB * 16 * 72 * 512 * 2;  // 37.75 MB
    unsigned short* xb  = (unsigned short*)(ws + off); off += (size_t)BB * 14 * 32 * 512 * 2;  // 14.68 MB
    unsigned short* wb2 = (unsigned short*)(ws + off); off += (size_t)S2 * NE * 2;             // 9.44 MB
    unsigned short* cwX = (unsigned short*)(ws + off); off += (size_t)BB * S1 * 2;             // 16.78 MB
    unsigned short* cw1 = cwX;
    unsigned short* cw3 = cwX;
    (void)ws_size;

    // Zero msum2+msum3+zpad (contiguous) in one memset.
    hipMemsetAsync(msum2, 0, (size_t)2 * BB * 256 * 4 + 256, stream);

    // Pre: transpose+mean of x (blocks 0-255) || permute w2 (blocks 256-2303).
    pre_kernel<<<2304, 256, 0, stream>>>(x, xb, mean1, w2, wb2);

    // Stage 1: 1x1 conv 1024->256
    combine_cont_r<<<dim3(128, 4), 256, 0, stream>>>(w1, mean1, r1_w, r1_b, 1.0f, INP,
                                                     cw1, S1, 16, 32);
    gemm1_fused<<<dim3(BB, 4, 2), 512, 0, stream>>>(xb, cw1, bn1_g, bn1_b, bn1_m, bn1_v,
                                                    act1, msum2);

    // Stage 2: 3x3 conv 256->256
    combine_w2_r<<<dim3(288, 4), 256, 0, stream>>>(wb2, msum2, r2_w, r2_b,
                                                   1.0f / (float)HW, cw2);
    gemm2_fused<<<dim3(BB, 4, 2), 512, 0, stream>>>(act1, cw2, zpad, bn2_g, bn2_b,
                                                    bn2_m, bn2_v, act2, msum3);

    // Stage 3: 1x1 conv 256->1024 + residual
    combine_cont_r<<<dim3(128, 4), 256, 0, stream>>>(w3, msum3, r3_w, r3_b,
                                                     1.0f / (float)HW, WIDTH,
                                                     cw3, S3, 64, 8);
    gemm3_fused<<<dim3(BB, 16), 512, 0, stream>>>(act2, cw3, bn3_g, bn3_b, bn3_m, bn3_v,
                                                  xb, out);
}

// Round 2
// 240.562 us; speedup vs baseline: 1.0357x; 1.0357x over previous
//
#include <hip/hip_runtime.h>
#include <hip/hip_bf16.h>

#define BB 32
#define INP 1024
#define WIDTH 256
#define OUTP 1024
#define NE 8
#define HW 196
#define HH 14
#define EPS 1e-5f

#define S1 (WIDTH * INP)        // 262144
#define S2 (WIDTH * WIDTH * 9)  // 589824
#define S3 (OUTP * WIDTH)       // 262144

typedef __attribute__((ext_vector_type(8))) short bf16x8;
typedef __attribute__((ext_vector_type(4))) float f32x4;
typedef __attribute__((ext_vector_type(8))) unsigned short u16x8;

// Swizzled operand layout: tile = 16 rows x 32 k = 512 bf16 = 1 KB.
// Element (r,k) at lane*8 + (k&7), lane = (r&15) | (((k>>3)&3)<<4).

__device__ __forceinline__ unsigned short f2bf_bits(float f) {
    unsigned u = __float_as_uint(f);
    u += 0x7FFFu + ((u >> 16) & 1u);   // RNE
    return (unsigned short)(u >> 16);
}
__device__ __forceinline__ float bf2f(unsigned short h) {
    return __uint_as_float((unsigned)h << 16);
}

#if defined(__has_builtin)
#if __has_builtin(__builtin_amdgcn_global_load_lds)
#define HAVE_GLL 1
#endif
#endif
__device__ __forceinline__ void gl2lds(const unsigned short* g, unsigned short* l,
                                       int lane) {
#ifdef HAVE_GLL
    __builtin_amdgcn_global_load_lds(
        (const __attribute__((address_space(1))) unsigned int*)(const void*)g,
        (__attribute__((address_space(3))) unsigned int*)(void*)l, 16, 0, 0);
#else
    *(u16x8*)(l + lane * 8) = *(const u16x8*)g;
#endif
}

// ---------------------------------------------------------------------------
// In-block routing (8-sample group g): srw[s*8+e] = sigmoid(scale*(v@W)+b).
// First 4 waves only participate meaningfully; block is 256 threads.
// ---------------------------------------------------------------------------
__device__ __forceinline__ void block_route(
    const float* __restrict__ vec, const float* __restrict__ W,
    const float* __restrict__ bias, float scale, int C, int g,
    float* srw, int tid) {
    int wv = tid >> 6, lane = tid & 63;
    float p0[NE], p1[NE];
#pragma unroll
    for (int e = 0; e < NE; e++) { p0[e] = 0.f; p1[e] = 0.f; }
    const float* v0 = vec + (size_t)(g * 8 + wv * 2) * C;
    const float* v1 = v0 + C;
    for (int c = lane; c < C; c += 64) {
        float4 wa = *(const float4*)(W + c * 8);
        float4 wb = *(const float4*)(W + c * 8 + 4);
        float m0 = v0[c], m1 = v1[c];
        p0[0] += m0 * wa.x; p0[1] += m0 * wa.y; p0[2] += m0 * wa.z; p0[3] += m0 * wa.w;
        p0[4] += m0 * wb.x; p0[5] += m0 * wb.y; p0[6] += m0 * wb.z; p0[7] += m0 * wb.w;
        p1[0] += m1 * wa.x; p1[1] += m1 * wa.y; p1[2] += m1 * wa.z; p1[3] += m1 * wa.w;
        p1[4] += m1 * wb.x; p1[5] += m1 * wb.y; p1[6] += m1 * wb.z; p1[7] += m1 * wb.w;
    }
#pragma unroll
    for (int j = 1; j < 64; j <<= 1) {
#pragma unroll
        for (int e = 0; e < NE; e++) {
            p0[e] += __shfl_xor(p0[e], j, 64);
            p1[e] += __shfl_xor(p1[e], j, 64);
        }
    }
    if (lane == 0) {
#pragma unroll
        for (int e = 0; e < NE; e++) {
            srw[(wv * 2) * 8 + e] = 1.0f / (1.0f + expf(-(scale * p0[e] + bias[e])));
            srw[(wv * 2 + 1) * 8 + e] = 1.0f / (1.0f + expf(-(scale * p1[e] + bias[e])));
        }
    }
    __syncthreads();
}

// ---------------------------------------------------------------------------
// Merged pre-kernel. Blocks [0,256): transpose+mean of x -> swizzled xb +
// mean1. Blocks [256,2304): permute w2 -> k-ordered bf16 wb2.
// ---------------------------------------------------------------------------
__global__ __launch_bounds__(256) void pre_kernel(
    const float* __restrict__ x, unsigned short* __restrict__ xb,
    float* __restrict__ mean1,
    const float* __restrict__ w2, unsigned short* __restrict__ wb2) {
    __shared__ __align__(16) char smem[128 * 17 * 4];
    int blk = blockIdx.x, t = threadIdx.x;
    if (blk < 256) {
        float (*lt)[17] = (float(*)[17])smem;
        int b = blk >> 3, yq = blk & 7, c0 = yq * 128;
        int cr = t >> 1, half = t & 1;
        const float* src = x + ((size_t)(b * INP + c0 + cr)) * HW;
        float msum = 0.f;
        int j = t >> 4, nl = t & 15;
        for (int pg = 0; pg < 14; pg++) {
            int p0 = pg * 16 + half * 8;
            float vv[8];
            if (pg < 12) {
                float4 a = *(const float4*)(src + p0);
                float4 c = *(const float4*)(src + p0 + 4);
                vv[0] = a.x; vv[1] = a.y; vv[2] = a.z; vv[3] = a.w;
                vv[4] = c.x; vv[5] = c.y; vv[6] = c.z; vv[7] = c.w;
            } else {
#pragma unroll
                for (int i = 0; i < 8; i++) {
                    int p = p0 + i;
                    vv[i] = (p < HW) ? src[p] : 0.f;
                }
            }
#pragma unroll
            for (int i = 0; i < 8; i++) { msum += vv[i]; lt[cr][half * 8 + i] = vv[i]; }
            __syncthreads();
            unsigned short pk[8];
#pragma unroll
            for (int i = 0; i < 8; i++) pk[i] = f2bf_bits(lt[j * 8 + i][nl]);
            size_t tile = ((size_t)b * 14 + pg) * 32 + (size_t)(yq * 4 + (j >> 2));
            int lane = nl | ((j & 3) << 4);
            *(u16x8*)(xb + tile * 512 + lane * 8) = *(u16x8*)pk;
            __syncthreads();
        }
        float other = __shfl_xor(msum, 1, 64);
        if (half == 0) mean1[b * INP + c0 + cr] = (msum + other) * (1.0f / (float)HW);
    } else {
        unsigned short* lds = (unsigned short*)smem;
        int eo = blk - 256;
        const float* src = w2 + (size_t)eo * 2304 + (size_t)t * 9;
#pragma unroll
        for (int t9 = 0; t9 < 9; t9++) lds[t9 * 256 + t] = f2bf_bits(src[t9]);
        __syncthreads();
        unsigned short* dst = wb2 + (size_t)eo * 2304;
        for (int j = t; j < 288; j += 256)
            *(u16x8*)(dst + j * 8) = *(const u16x8*)(lds + j * 8);
    }
}

// ---------------------------------------------------------------------------
// Combine (contiguous-k fp32 experts, w1/w3) + fused routing.
// grid = (Mt*Kt/4, 4 sample groups), 256 threads.
// ---------------------------------------------------------------------------
__global__ __launch_bounds__(256) void combine_cont_r(
    const float* __restrict__ w, const float* __restrict__ vec,
    const float* __restrict__ rW, const float* __restrict__ rB, float scale, int C,
    unsigned short* __restrict__ cw, int S, int Mt, int Kt) {
    __shared__ float srw[64];
    int tid = threadIdx.x, wv = tid >> 6, lane = tid & 63, ml = lane & 15, k8l = lane >> 4;
    int g = blockIdx.y;
    block_route(vec, rW, rB, scale, C, g, srw, tid);
    int kq = Kt >> 2;
    int mt = blockIdx.x / kq, kt = (blockIdx.x - mt * kq) * 4 + wv;
    int K = Kt * 32;
    const float* src = w + (size_t)(mt * 16 + ml) * K + kt * 32 + k8l * 8;
    float v[NE][8];
#pragma unroll
    for (int e = 0; e < NE; e++) {
        float4 a = *(const float4*)(src + (size_t)e * S);
        float4 c = *(const float4*)(src + (size_t)e * S + 4);
        v[e][0] = a.x; v[e][1] = a.y; v[e][2] = a.z; v[e][3] = a.w;
        v[e][4] = c.x; v[e][5] = c.y; v[e][6] = c.z; v[e][7] = c.w;
    }
    size_t dto = ((size_t)mt * Kt + kt) * 512 + (size_t)lane * 8;
    size_t bstr = (size_t)Mt * Kt * 512;
    for (int bl = 0; bl < 8; bl++) {
        int b = g * 8 + bl;
        float acc[8];
#pragma unroll
        for (int jj = 0; jj < 8; jj++) acc[jj] = 0.f;
#pragma unroll
        for (int e = 0; e < NE; e++) {
            float r = srw[bl * NE + e];
#pragma unroll
            for (int jj = 0; jj < 8; jj++) acc[jj] += r * v[e][jj];
        }
        u16x8 o;
#pragma unroll
        for (int jj = 0; jj < 8; jj++) o[jj] = f2bf_bits(acc[jj]);
        *(u16x8*)(cw + (size_t)b * bstr + dto) = o;
    }
}

// ---------------------------------------------------------------------------
// Combine w2 (k-ordered bf16 wb2) + fused routing. grid = (288, 4 groups).
// ---------------------------------------------------------------------------
__global__ __launch_bounds__(256) void combine_w2_r(
    const unsigned short* __restrict__ wb2, const float* __restrict__ vec,
    const float* __restrict__ rW, const float* __restrict__ rB, float scale,
    unsigned short* __restrict__ cw) {
    __shared__ float srw[64];
    int tid = threadIdx.x, wv = tid >> 6, lane = tid & 63, ol = lane & 15, g4 = lane >> 4;
    int g = blockIdx.y;
    block_route(vec, rW, rB, scale, 256, g, srw, tid);
    int ot = blockIdx.x / 18, kt = (blockIdx.x - ot * 18) * 4 + wv;
    const unsigned short* src = wb2 + (size_t)(ot * 16 + ol) * 2304 + kt * 32 + g4 * 8;
    float v[NE][8];
#pragma unroll
    for (int e = 0; e < NE; e++) {
        u16x8 raw = *(const u16x8*)(src + (size_t)e * S2);
#pragma unroll
        for (int jj = 0; jj < 8; jj++) v[e][jj] = bf2f(raw[jj]);
    }
    size_t dto = ((size_t)ot * 72 + kt) * 512 + (size_t)lane * 8;
    for (int bl = 0; bl < 8; bl++) {
        int b = g * 8 + bl;
        float acc[8];
#pragma unroll
        for (int jj = 0; jj < 8; jj++) acc[jj] = 0.f;
#pragma unroll
        for (int e = 0; e < NE; e++) {
            float r = srw[bl * NE + e];
#pragma unroll
            for (int jj = 0; jj < 8; jj++) acc[jj] += r * v[e][jj];
        }
        u16x8 out;
#pragma unroll
        for (int jj = 0; jj < 8; jj++) out[jj] = f2bf_bits(acc[jj]);
        *(u16x8*)(cw + (size_t)b * (16 * 72 * 512) + dto) = out;
    }
}

// ---------------------------------------------------------------------------
// Fused epilogue: BN + ReLU -> swizzled bf16 act + per-channel sum atomics.
// Handles nB (3 or 4) n-tiles starting at nt0.
// ---------------------------------------------------------------------------
__device__ __forceinline__ void epilogue_act(
    const f32x4* acc, int b, int mt, int nt0, int nB, int lo, int g4,
    const float* __restrict__ g, const float* __restrict__ be,
    const float* __restrict__ mu, const float* __restrict__ var,
    unsigned short* __restrict__ actout, float* __restrict__ msum) {
    int c0 = mt * 16 + g4 * 4;
    float sc[4], sh[4];
#pragma unroll
    for (int r = 0; r < 4; r++) {
        float iv = rsqrtf(var[c0 + r] + EPS) * g[c0 + r];
        sc[r] = iv;
        sh[r] = be[c0 + r] - mu[c0 + r] * iv;
    }
    float ms[4] = {0.f, 0.f, 0.f, 0.f};
    int ktc = mt >> 1;
    int lanehi = ((mt * 2 + (g4 >> 1)) & 3) << 4;
#pragma unroll
    for (int t = 0; t < 4; t++) {
        if (t >= nB) break;
        int nt = nt0 + t;
        int n = nt * 16 + lo;
        float v[4];
#pragma unroll
        for (int r = 0; r < 4; r++) {
            float val = acc[t][r] * sc[r] + sh[r];
            val = fmaxf(val, 0.f);
            if (n >= HW) val = 0.f;
            v[r] = val;
            ms[r] += val;
        }
        unsigned p01 = (unsigned)f2bf_bits(v[0]) | ((unsigned)f2bf_bits(v[1]) << 16);
        unsigned p23 = (unsigned)f2bf_bits(v[2]) | ((unsigned)f2bf_bits(v[3]) << 16);
        size_t off = (((size_t)(b * 14 + nt)) * 8 + ktc) * 512 + (size_t)(lo | lanehi) * 8 + (g4 & 1) * 4;
        *(uint2*)(actout + off) = make_uint2(p01, p23);
    }
#pragma unroll
    for (int r = 0; r < 4; r++) {
        float s = ms[r];
        s += __shfl_xor(s, 1, 64);
        s += __shfl_xor(s, 2, 64);
        s += __shfl_xor(s, 4, 64);
        s += __shfl_xor(s, 8, 64);
        if (lo == 0) atomicAdd(&msum[b * 256 + c0 + r], s);
    }
}

// ---------------------------------------------------------------------------
// Stage-1 fused GEMM, 512 threads = 8 waves, in-block split-K2:
// group = wave>>2 computes k-steps of parity `group`; partials reduced via
// LDS at the end; group 0 runs the fused epilogue.
// n-axis split in 4 chunks (4,4,3,3 tiles) -> grid (BB,4,4) = 512 blocks
// = 2 blocks/CU so barrier-drain stalls overlap across blocks. LDS 32 KB.
// ---------------------------------------------------------------------------
__global__ __launch_bounds__(512) void gemm1_fused(
    const unsigned short* __restrict__ Bsw, const unsigned short* __restrict__ Asw,
    const float* __restrict__ g, const float* __restrict__ be,
    const float* __restrict__ mu, const float* __restrict__ var,
    unsigned short* __restrict__ actout, float* __restrict__ msum) {
    __shared__ __align__(16) unsigned short lAb[4][4 * 512];   // 16 KB
    __shared__ __align__(16) unsigned short lBb[4][4 * 512];   // 16 KB
    const int Kt = 32;
    int b = blockIdx.x, mh = blockIdx.y, z = blockIdx.z;
    int nt0 = (z < 3) ? z * 4 : 11;
    int nB = (z < 2) ? 4 : 3;
    int tid = threadIdx.x, wv = tid >> 6, grp = wv >> 2, wl = wv & 3;
    int lane = tid & 63, lo = lane & 15, g4 = lane >> 4;
    const unsigned short* Ab = Asw + (size_t)(b * 16 + mh * 4) * Kt * 512;
    const unsigned short* Bb = Bsw + (size_t)(b * 14 + nt0) * Kt * 512;
    f32x4 acc[4];
#pragma unroll
    for (int t = 0; t < 4; t++) acc[t] = {0.f, 0.f, 0.f, 0.f};

    auto stage = [&](int kt, unsigned short* lA, unsigned short* lB) {
        gl2lds(Ab + ((size_t)wl * Kt + kt) * 512 + lane * 8, lA + wl * 512, lane);
        if (wl < nB)
            gl2lds(Bb + ((size_t)wl * Kt + kt) * 512 + lane * 8, lB + wl * 512, lane);
    };
    auto compute = [&](const unsigned short* lA, const unsigned short* lB) {
        bf16x8 a0 = *(const bf16x8*)(lA + wl * 512 + lane * 8);
#pragma unroll
        for (int t = 0; t < 4; t++) {
            if (t >= nB) break;
            bf16x8 bt = *(const bf16x8*)(lB + t * 512 + lane * 8);
            acc[t] = __builtin_amdgcn_mfma_f32_16x16x32_bf16(a0, bt, acc[t], 0, 0, 0);
        }
    };

    // Pre-stage steps 0 (group 0) and 1 (group 1).
    stage(grp, lAb[grp], lBb[grp]);
    for (int kp = 0; kp < 16; kp++) {
        __syncthreads();
        if (kp < 15) {
            int s = 2 * kp + 2 + grp;
            stage(s, lAb[s & 3], lBb[s & 3]);
        }
        int c = (2 * kp + grp) & 3;
        compute(lAb[c], lBb[c]);
    }
    // Cross-group reduction through (dead) B-staging LDS (16 KB exactly).
    __syncthreads();
    float* red = (float*)&lBb[0][0];
    if (grp == 1) {
#pragma unroll
        for (int t = 0; t < 4; t++)
            *(f32x4*)(red + (((size_t)wl * 4 + t) * 64 + lane) * 4) = acc[t];
    }
    __syncthreads();
    if (grp == 0) {
#pragma unroll
        for (int t = 0; t < 4; t++) {
            f32x4 o = *(const f32x4*)(red + (((size_t)wl * 4 + t) * 64 + lane) * 4);
#pragma unroll
            for (int r = 0; r < 4; r++) acc[t][r] += o[r];
        }
        epilogue_act(acc, b, mh * 4 + wl, nt0, nB, lo, g4, g, be, mu, var, actout, msum);
    }
}

// ---------------------------------------------------------------------------
// Stage-2 fused GEMM (im2col gather staging), 512 threads, in-block split-K2.
// n-axis split in 4 chunks -> grid (BB,4,4) = 512 blocks = 2 blocks/CU.
// 72 k-steps (9 taps x 8 i-tiles). LDS 32 KB.
// ---------------------------------------------------------------------------
__global__ __launch_bounds__(512) void gemm2_fused(
    const unsigned short* __restrict__ act, const unsigned short* __restrict__ cw2,
    const unsigned short* __restrict__ zpad,
    const float* __restrict__ g, const float* __restrict__ be,
    const float* __restrict__ mu, const float* __restrict__ var,
    unsigned short* __restrict__ actout, float* __restrict__ msum) {
    __shared__ __align__(16) unsigned short lAb[4][4 * 512];   // 16 KB
    __shared__ __align__(16) unsigned short lBb[4][4 * 512];   // 16 KB
    int b = blockIdx.x, mh = blockIdx.y, z = blockIdx.z;
    int nt0 = (z < 3) ? z * 4 : 11;
    int nB = (z < 2) ? 4 : 3;
    int tid = threadIdx.x, wv = tid >> 6, grp = wv >> 2, wl = wv & 3;
    int lane = tid & 63, lo = lane & 15, g4 = lane >> 4;
    const unsigned short* Ab = cw2 + (size_t)(b * 16 + mh * 4) * 72 * 512;
    const unsigned short* actb = act + (size_t)b * 14 * 8 * 512;

    int p0 = (nt0 + wl) * 16 + lo;
    int py0 = p0 / HH, px0 = p0 - (p0 / HH) * HH;
    bool pv0 = (wl < nB) && (p0 < HW);

    f32x4 acc[4];
#pragma unroll
    for (int t = 0; t < 4; t++) acc[t] = {0.f, 0.f, 0.f, 0.f};

    auto stage = [&](int kt, unsigned short* lA, unsigned short* lB) {
        gl2lds(Ab + ((size_t)wl * 72 + kt) * 512 + lane * 8, lA + wl * 512, lane);
        if (wl < nB) {
            int t9 = kt >> 3;
            int dy = t9 / 3 - 1, dx = t9 - (t9 / 3) * 3 - 1;
            int itile = kt & 7;
            int sy = py0 + dy, sx = px0 + dx;
            bool ok = pv0 && sy >= 0 && sy < HH && sx >= 0 && sx < HH;
            int ns = sy * HH + sx;
            const unsigned short* gp = ok
                ? actb + ((size_t)(ns >> 4) * 8 + itile) * 512 + (size_t)((ns & 15) | (g4 << 4)) * 8
                : zpad;
            gl2lds(gp, lB + wl * 512, lane);
        }
    };
    auto compute = [&](const unsigned short* lA, const unsigned short* lB) {
        bf16x8 a0 = *(const bf16x8*)(lA + wl * 512 + lane * 8);
#pragma unroll
        for (int t = 0; t < 4; t++) {
            if (t >= nB) break;
            bf16x8 bt = *(const bf16x8*)(lB + t * 512 + lane * 8);
            acc[t] = __builtin_amdgcn_mfma_f32_16x16x32_bf16(a0, bt, acc[t], 0, 0, 0);
        }
    };

    stage(grp, lAb[grp], lBb[grp]);
    for (int kp = 0; kp < 36; kp++) {
        __syncthreads();
        if (kp < 35) {
            int s = 2 * kp + 2 + grp;
            stage(s, lAb[s & 3], lBb[s & 3]);
        }
        int c = (2 * kp + grp) & 3;
        compute(lAb[c], lBb[c]);
    }
    __syncthreads();
    float* red = (float*)&lBb[0][0];
    if (grp == 1) {
#pragma unroll
        for (int t = 0; t < 4; t++)
            *(f32x4*)(red + (((size_t)wl * 4 + t) * 64 + lane) * 4) = acc[t];
    }
    __syncthreads();
    if (grp == 0) {
#pragma unroll
        for (int t = 0; t < 4; t++) {
            f32x4 o = *(const f32x4*)(red + (((size_t)wl * 4 + t) * 64 + lane) * 4);
#pragma unroll
            for (int r = 0; r < 4; r++) acc[t][r] += o[r];
        }
        epilogue_act(acc, b, mh * 4 + wl, nt0, nB, lo, g4, g, be, mu, var, actout, msum);
    }
}

// ---------------------------------------------------------------------------
// Stage-3 GEMM, 512 threads, in-block split-K2, fused BN + bf16 residual
// (from swizzled xb) + ReLU -> fp32 NCHW. grid (BB, 16) = 512 blocks
// (already 2 blocks/CU at 60 KB LDS). K=256 (8 steps).
// ---------------------------------------------------------------------------
__global__ __launch_bounds__(512) void gemm3_fused(
    const unsigned short* __restrict__ Bsw, const unsigned short* __restrict__ Asw,
    const float* __restrict__ g, const float* __restrict__ be,
    const float* __restrict__ mu, const float* __restrict__ var,
    const unsigned short* __restrict__ xb, float* __restrict__ out) {
    __shared__ __align__(16) unsigned short lAb[4][8 * 512];
    __shared__ __align__(16) unsigned short lBb[4][7 * 512];
    int b = blockIdx.x, y = blockIdx.y, mh = y >> 1, nh = y & 1;
    int tid = threadIdx.x, wv = tid >> 6, grp = wv >> 2, wl = wv & 3;
    int lane = tid & 63, lo = lane & 15, g4 = lane >> 4;
    const unsigned short* Ab = Asw + (size_t)(b * 64 + mh * 8) * 8 * 512;
    const unsigned short* Bb = Bsw + (size_t)(b * 14 + nh * 7) * 8 * 512;
    f32x4 acc0[7], acc1[7];
#pragma unroll
    for (int t = 0; t < 7; t++) { acc0[t] = {0.f, 0.f, 0.f, 0.f}; acc1[t] = {0.f, 0.f, 0.f, 0.f}; }

    auto stage = [&](int kt, unsigned short* lA, unsigned short* lB) {
        gl2lds(Ab + ((size_t)wl * 8 + kt) * 512 + lane * 8, lA + wl * 512, lane);
        gl2lds(Ab + ((size_t)(wl + 4) * 8 + kt) * 512 + lane * 8, lA + (wl + 4) * 512, lane);
        gl2lds(Bb + ((size_t)wl * 8 + kt) * 512 + lane * 8, lB + wl * 512, lane);
        if (wl < 3)
            gl2lds(Bb + ((size_t)(4 + wl) * 8 + kt) * 512 + lane * 8, lB + (4 + wl) * 512, lane);
    };
    auto compute = [&](const unsigned short* lA, const unsigned short* lB) {
        bf16x8 a0 = *(const bf16x8*)(lA + wl * 512 + lane * 8);
        bf16x8 a1 = *(const bf16x8*)(lA + (wl + 4) * 512 + lane * 8);
#pragma unroll
        for (int t = 0; t < 7; t++) {
            bf16x8 bt = *(const bf16x8*)(lB + t * 512 + lane * 8);
            acc0[t] = __builtin_amdgcn_mfma_f32_16x16x32_bf16(a0, bt, acc0[t], 0, 0, 0);
            acc1[t] = __builtin_amdgcn_mfma_f32_16x16x32_bf16(a1, bt, acc1[t], 0, 0, 0);
        }
    };

    stage(grp, lAb[grp], lBb[grp]);
    for (int kp = 0; kp < 4; kp++) {
        __syncthreads();
        if (kp < 3) {
            int s = 2 * kp + 2 + grp;
            stage(s, lAb[s & 3], lBb[s & 3]);
        }
        int c = (2 * kp + grp) & 3;
        compute(lAb[c], lBb[c]);
    }
    // Two-phase cross-group reduction via lBb (28672 B per phase).
    __syncthreads();
    float* red = (float*)&lBb[0][0];
    if (grp == 1) {
#pragma unroll
        for (int t = 0; t < 7; t++)
            *(f32x4*)(red + (((size_t)wl * 7 + t) * 64 + lane) * 4) = acc0[t];
    }
    __syncthreads();
    if (grp == 0) {
#pragma unroll
        for (int t = 0; t < 7; t++) {
            f32x4 o = *(const f32x4*)(red + (((size_t)wl * 7 + t) * 64 + lane) * 4);
#pragma unroll
            for (int r = 0; r < 4; r++) acc0[t][r] += o[r];
        }
    }
    __syncthreads();
    if (grp == 1) {
#pragma unroll
        for (int t = 0; t < 7; t++)
            *(f32x4*)(red + (((size_t)wl * 7 + t) * 64 + lane) * 4) = acc1[t];
    }
    __syncthreads();
    if (grp != 0) return;
#pragma unroll
    for (int t = 0; t < 7; t++) {
        f32x4 o = *(const f32x4*)(red + (((size_t)wl * 7 + t) * 64 + lane) * 4);
#pragma unroll
        for (int r = 0; r < 4; r++) acc1[t][r] += o[r];
    }

#pragma unroll
    for (int a = 0; a < 2; a++) {
        int mt = mh * 8 + wl + 4 * a;
        int c0 = mt * 16 + g4 * 4;
        float sc[4], sh[4];
#pragma unroll
        for (int r = 0; r < 4; r++) {
            float iv = rsqrtf(var[c0 + r] + EPS) * g[c0 + r];
            sc[r] = iv;
            sh[r] = be[c0 + r] - mu[c0 + r] * iv;
        }
        int ktc = mt >> 1;
        int lanehi = ((mt * 2 + (g4 >> 1)) & 3) << 4;
#pragma unroll
        for (int t = 0; t < 7; t++) {
            int nt = nh * 7 + t;
            int n = nt * 16 + lo;
            if (n >= HW) continue;
            // bf16 residual from swizzled xb (K-tiles of 32 over c=0..1023).
            const unsigned short* xr = xb + (((size_t)(b * 14 + nt)) * 32 + ktc) * 512
                                       + (size_t)(lo | lanehi) * 8 + (g4 & 1) * 4;
            uint2 rv = *(const uint2*)xr;
            float res[4] = {bf2f((unsigned short)(rv.x & 0xffff)),
                            bf2f((unsigned short)(rv.x >> 16)),
                            bf2f((unsigned short)(rv.y & 0xffff)),
                            bf2f((unsigned short)(rv.y >> 16))};
            f32x4 av = a ? acc1[t] : acc0[t];
#pragma unroll
            for (int r = 0; r < 4; r++) {
                size_t oidx = ((size_t)(b * OUTP + c0 + r)) * HW + n;
                float val = av[r] * sc[r] + sh[r] + res[r];
                out[oidx] = fmaxf(val, 0.f);
            }
        }
    }
}

// ---------------------------------------------------------------------------
extern "C" void kernel_launch(void* const* d_in, const int* in_sizes, int n_in,
                              void* d_out, int out_size, void* d_ws, size_t ws_size,
                              hipStream_t stream) {
    const float* x    = (const float*)d_in[0];
    const float* w1   = (const float*)d_in[1];
    const float* w2   = (const float*)d_in[2];
    const float* w3   = (const float*)d_in[3];
    const float* r1_w = (const float*)d_in[4];
    const float* r1_b = (const float*)d_in[5];
    const float* r2_w = (const float*)d_in[6];
    const float* r2_b = (const float*)d_in[7];
    const float* r3_w = (const float*)d_in[8];
    const float* r3_b = (const float*)d_in[9];
    const float* bn1_g = (const float*)d_in[10];
    const float* bn1_b = (const float*)d_in[11];
    const float* bn1_m = (const float*)d_in[12];
    const float* bn1_v = (const float*)d_in[13];
    const float* bn2_g = (const float*)d_in[14];
    const float* bn2_b = (const float*)d_in[15];
    const float* bn2_m = (const float*)d_in[16];
    const float* bn2_v = (const float*)d_in[17];
    const float* bn3_g = (const float*)d_in[18];
    const float* bn3_b = (const float*)d_in[19];
    const float* bn3_m = (const float*)d_in[20];
    const float* bn3_v = (const float*)d_in[21];
    float* out = (float*)d_out;

    // Workspace (~86.4 MB). cwX slot time-shared: cw1 (stage 1) then cw3
    // (stage 3; cw1 dead after gemm1). xb persists to gemm3 (bf16 residual).
    char* ws = (char*)d_ws;
    size_t off = 0;
    float* mean1 = (float*)(ws + off); off += (size_t)BB * INP * 4;
    float* msum2 = (float*)(ws + off); off += (size_t)BB * 256 * 4;
    float* msum3 = (float*)(ws + off); off += (size_t)BB * 256 * 4;
    unsigned short* zpad = (unsigned short*)(ws + off); off += 256;
    off = (off + 255) & ~(size_t)255;
    unsigned short* act1 = (unsigned short*)(ws + off); off += (size_t)BB * 14 * 8 * 512 * 2;  // 3.67 MB
    unsigned short* act2 = (unsigned short*)(ws + off); off += (size_t)BB * 14 * 8 * 512 * 2;  // 3.67 MB
    unsigned short* cw2 = (unsigned short*)(ws + off); off += (size_t)BB * 16 * 72 * 512 * 2;  // 37.75 MB
    unsigned short* xb  = (unsigned short*)(ws + off); off += (size_t)BB * 14 * 32 * 512 * 2;  // 14.68 MB
    unsigned short* wb2 = (unsigned short*)(ws + off); off += (size_t)S2 * NE * 2;             // 9.44 MB
    unsigned short* cwX = (unsigned short*)(ws + off); off += (size_t)BB * S1 * 2;             // 16.78 MB
    unsigned short* cw1 = cwX;
    unsigned short* cw3 = cwX;
    (void)ws_size;

    // Zero msum2+msum3+zpad (contiguous) in one memset.
    hipMemsetAsync(msum2, 0, (size_t)2 * BB * 256 * 4 + 256, stream);

    // Pre: transpose+mean of x (blocks 0-255) || permute w2 (blocks 256-2303).
    pre_kernel<<<2304, 256, 0, stream>>>(x, xb, mean1, w2, wb2);

    // Stage 1: 1x1 conv 1024->256
    combine_cont_r<<<dim3(128, 4), 256, 0, stream>>>(w1, mean1, r1_w, r1_b, 1.0f, INP,
                                                     cw1, S1, 16, 32);
    gemm1_fused<<<dim3(BB, 4, 4), 512, 0, stream>>>(xb, cw1, bn1_g, bn1_b, bn1_m, bn1_v,
                                                    act1, msum2);

    // Stage 2: 3x3 conv 256->256
    combine_w2_r<<<dim3(288, 4), 256, 0, stream>>>(wb2, msum2, r2_w, r2_b,
                                                   1.0f / (float)HW, cw2);
    gemm2_fused<<<dim3(BB, 4, 4), 512, 0, stream>>>(act1, cw2, zpad, bn2_g, bn2_b,
                                                    bn2_m, bn2_v, act2, msum3);

    // Stage 3: 1x1 conv 256->1024 + residual
    combine_cont_r<<<dim3(128, 4), 256, 0, stream>>>(w3, msum3, r3_w, r3_b,
                                                     1.0f / (float)HW, WIDTH,
                                                     cw3, S3, 64, 8);
    gemm3_fused<<<dim3(BB, 16), 512, 0, stream>>>(act2, cw3, bn3_g, bn3_b, bn3_m, bn3_v,
                                                  xb, out);
}